// Round 5
// baseline (198.910 us; speedup 1.0000x reference)
//
#include <hip/hip_runtime.h>

#define AS1 __attribute__((address_space(1)))
#define AS3 __attribute__((address_space(3)))

typedef short short8 __attribute__((ext_vector_type(8)));
typedef float f32x16 __attribute__((ext_vector_type(16)));

// Problem constants
#define BATCH 4096
#define IN_F 256
#define OUT_F 256
#define HYP 128
#define HX 129            // HYP + 1 (b2g folded in as extra channel, gain 1.0)
#define KP (HX * IN_F)    // 33024 shorts per V row
#define NGEMMP 32         // prep GEMM blocks (M-tile 128)
#define NVB 516           // V-build blocks (2048 cids each; 256*129*32 / 2048)

__device__ __forceinline__ float bf2f(unsigned short u) {
  unsigned v = ((unsigned)u) << 16;
  float f;
  __builtin_memcpy(&f, &v, 4);
  return f;
}
__device__ __forceinline__ unsigned short f2bf(float f) {
  unsigned u;
  __builtin_memcpy(&u, &f, 4);
  unsigned r = u + 0x7fffu + ((u >> 16) & 1u);  // RTNE
  return (unsigned short)(r >> 16);
}

__device__ __forceinline__ void gld_lds16(const unsigned short* g, unsigned short* s) {
  __builtin_amdgcn_global_load_lds((const AS1 unsigned int*)g, (AS3 unsigned int*)s, 16, 0, 0);
}

// ---------------------------------------------------------------------------
// k_trans: build bf16 transposed weight views so MFMA operands are
// k-contiguous.  W1T[n][k] (n<128: W1g^T, n>=128: W1b^T), W2bT[o][h].
// ---------------------------------------------------------------------------
__global__ __launch_bounds__(256) void k_trans(const float* __restrict__ W1g,
                                               const float* __restrict__ W1b,
                                               const float* __restrict__ W2b,
                                               unsigned short* __restrict__ W1T,
                                               unsigned short* __restrict__ W2bT) {
  const int t = threadIdx.x, b = blockIdx.x;
  if (b < 64) {
#pragma unroll
    for (int i = 0; i < 4; ++i) {
      const int e = b * 1024 + i * 256 + t;   // < 65536
      const int n = e >> 8, k = e & 255;
      const float v = (n < HYP) ? W1g[k * HYP + n] : W1b[k * HYP + (n - HYP)];
      W1T[e] = f2bf(v);
    }
  } else {
#pragma unroll
    for (int i = 0; i < 4; ++i) {
      const int e = (b - 64) * 1024 + i * 256 + t;  // < 32768
      const int o = e >> 7, h = e & 127;
      W2bT[e] = f2bf(W2b[h * OUT_F + o]);
    }
  }
}

// ---------------------------------------------------------------------------
// k_prep: blocks [0,NGEMMP): MFMA prep GEMMs, M-tile 128, 8 waves.
// blocks [NGEMMP, NGEMMP+NVB): V build.  (verified round-2 kernel, unchanged)
// ---------------------------------------------------------------------------
__global__ __launch_bounds__(512) void k_prep(
    const float* __restrict__ x,
    const float* __restrict__ b1g, const float* __restrict__ b1b,
    const float* __restrict__ b2b,
    const float* __restrict__ W2g, const float* __restrict__ b2g,
    const unsigned short* __restrict__ W1T, const unsigned short* __restrict__ W2bT,
    unsigned short* __restrict__ Vb, unsigned short* __restrict__ hgbT,
    unsigned short* __restrict__ xb, float* __restrict__ out) {
  __shared__ __align__(16) unsigned short xS[128 * 256];   // 64 KB, chunk^row&31 swizzle
  __shared__ __align__(16) unsigned short hbS[128 * 128];  // 32 KB, chunk^m&15 swizzle
  const int t = threadIdx.x;

  if (blockIdx.x >= NGEMMP) {
    const int base = (blockIdx.x - NGEMMP) * 2048 + t;
#pragma unroll
    for (int it = 0; it < 4; ++it) {
      const int cid = base + it * 512;
      const int ic = cid & 31;
      const int pair = cid >> 5;        // o*129 + h
      const int h = pair % HX;
      const int o = pair / HX;
      const float* src = (h < HYP) ? (W2g + (size_t)h * (OUT_F * IN_F) + o * IN_F + ic * 8)
                                   : (b2g + o * IN_F + ic * 8);
      const float4 v0 = ((const float4*)src)[0];
      const float4 v1 = ((const float4*)src)[1];
      uint4 pk;
      pk.x = (unsigned)f2bf(v0.x) | ((unsigned)f2bf(v0.y) << 16);
      pk.y = (unsigned)f2bf(v0.z) | ((unsigned)f2bf(v0.w) << 16);
      pk.z = (unsigned)f2bf(v1.x) | ((unsigned)f2bf(v1.y) << 16);
      pk.w = (unsigned)f2bf(v1.z) | ((unsigned)f2bf(v1.w) << 16);
      *(uint4*)(Vb + (size_t)o * KP + h * IN_F + ic * 8) = pk;
    }
    return;
  }

  const int lane = t & 63;
  const int w = t >> 6;            // 0..7
  const int l31 = lane & 31;
  const int hi = lane >> 5;
  const int m0 = blockIdx.x * 128;

#pragma unroll
  for (int j = 0; j < 16; ++j) {
    const int row = j * 8 + w;                       // 0..127, each once
    const float4 v = *(const float4*)(x + (size_t)(m0 + row) * IN_F + lane * 4);
    uint2 pk;
    pk.x = (unsigned)f2bf(v.x) | ((unsigned)f2bf(v.y) << 16);
    pk.y = (unsigned)f2bf(v.z) | ((unsigned)f2bf(v.w) << 16);
    *(uint2*)(xb + (size_t)(m0 + row) * IN_F + lane * 4) = pk;
    const int ch = lane >> 1, half = lane & 1;       // 16B chunk, 8B half
    *(uint2*)(&xS[row * 256 + ((ch ^ (row & 31))) * 8 + half * 4]) = pk;
  }
  __syncthreads();

  const int hA = w * 32 + l31;                       // 0..255 (g: <128, b: >=128)
  uint4 af[16];
#pragma unroll
  for (int kt = 0; kt < 16; ++kt)
    af[kt] = *(const uint4*)(W1T + (size_t)hA * 256 + kt * 16 + hi * 8);

  f32x16 zv;
#pragma unroll
  for (int i = 0; i < 16; ++i) zv[i] = 0.0f;
  f32x16 d0 = zv, d1 = zv, d2 = zv, d3 = zv;
#pragma unroll
  for (int kt = 0; kt < 16; ++kt) {
    const int pos = (kt * 2 + hi) ^ l31;             // (m&31) == l31 for all csub
    const short8 a = __builtin_bit_cast(short8, af[kt]);
#define G1STEP(CS, DD)                                                        \
    {                                                                         \
      const short8 bfrg = *(const short8*)(&xS[(CS * 32 + l31) * 256 + pos * 8]); \
      DD = __builtin_amdgcn_mfma_f32_32x32x16_bf16(a, bfrg, DD, 0, 0, 0);     \
    }
    G1STEP(0, d0) G1STEP(1, d1) G1STEP(2, d2) G1STEP(3, d3)
#undef G1STEP
  }

  if (w < 4) {
    float4 bq[4];
#pragma unroll
    for (int q = 0; q < 4; ++q)
      bq[q] = *(const float4*)(b1g + w * 32 + q * 8 + hi * 4);
#define EPI_G(CS, DD)                                                         \
    {                                                                         \
      const int mcol = m0 + CS * 32 + l31;                                    \
      _Pragma("unroll")                                                       \
      for (int g = 0; g < 16; ++g) {                                          \
        const int h = w * 32 + (g & 3) + 8 * (g >> 2) + 4 * hi;               \
        float v = DD[g] + ((const float*)&bq[g >> 2])[g & 3];                 \
        v = v > 0.f ? v : 0.f;                                                \
        hgbT[(size_t)h * BATCH + mcol] = f2bf(v);                             \
      }                                                                       \
    }
    EPI_G(0, d0) EPI_G(1, d1) EPI_G(2, d2) EPI_G(3, d3)
#undef EPI_G
  } else {
    float4 bq[4];
#pragma unroll
    for (int q = 0; q < 4; ++q)
      bq[q] = *(const float4*)(b1b + (w - 4) * 32 + q * 8 + hi * 4);
#define EPI_B(CS, DD)                                                         \
    {                                                                         \
      const int m = CS * 32 + l31;                                            \
      _Pragma("unroll")                                                       \
      for (int q = 0; q < 4; ++q) {                                           \
        float v0 = DD[q * 4 + 0] + ((const float*)&bq[q])[0];                 \
        float v1 = DD[q * 4 + 1] + ((const float*)&bq[q])[1];                 \
        float v2 = DD[q * 4 + 2] + ((const float*)&bq[q])[2];                 \
        float v3 = DD[q * 4 + 3] + ((const float*)&bq[q])[3];                 \
        v0 = v0 > 0.f ? v0 : 0.f; v1 = v1 > 0.f ? v1 : 0.f;                   \
        v2 = v2 > 0.f ? v2 : 0.f; v3 = v3 > 0.f ? v3 : 0.f;                   \
        uint2 pk;                                                             \
        pk.x = (unsigned)f2bf(v0) | ((unsigned)f2bf(v1) << 16);               \
        pk.y = (unsigned)f2bf(v2) | ((unsigned)f2bf(v3) << 16);               \
        const int chunk = (w - 4) * 4 + q;                                    \
        *(uint2*)(&hbS[m * 128 + ((chunk ^ (m & 15))) * 8 + hi * 4]) = pk;    \
      }                                                                       \
    }
    EPI_B(0, d0) EPI_B(1, d1) EPI_B(2, d2) EPI_B(3, d3)
#undef EPI_B
  }
  __syncthreads();

  const int msub = w & 3, oh = w >> 2;
  const int mA = msub * 32 + l31;
  f32x16 e0 = zv, e1 = zv, e2 = zv, e3 = zv;
#pragma unroll
  for (int kt = 0; kt < 8; ++kt) {
    const int pos = (kt * 2 + hi) ^ (mA & 15);
    const short8 a = *(const short8*)(&hbS[mA * 128 + pos * 8]);
#define G2STEP(OS, EE)                                                        \
    {                                                                         \
      const int orow = oh * 128 + OS * 32 + l31;                              \
      const short8 bb = *(const short8*)(W2bT + (size_t)orow * 128 + kt * 16 + hi * 8); \
      EE = __builtin_amdgcn_mfma_f32_32x32x16_bf16(a, bb, EE, 0, 0, 0);       \
    }
    G2STEP(0, e0) G2STEP(1, e1) G2STEP(2, e2) G2STEP(3, e3)
#undef G2STEP
  }
#define EPI2(OS, EE)                                                          \
  {                                                                           \
    const int o = oh * 128 + OS * 32 + l31;                                   \
    const float bo = b2b[o];                                                  \
    _Pragma("unroll")                                                         \
    for (int g = 0; g < 16; ++g) {                                            \
      const int m = m0 + msub * 32 + (g & 3) + 8 * (g >> 2) + 4 * hi;         \
      out[(size_t)m * OUT_F + o] = EE[g] + bo;                                \
    }                                                                         \
  }
  EPI2(0, e0) EPI2(1, e1) EPI2(2, e2) EPI2(3, e3)
#undef EPI2
}

// ---------------------------------------------------------------------------
// k_gemm: out[b,o] += sum_h hg[b,h] * (sum_i V[o][h*256+i]*x[b,i])
// Round-2 tiling (M=256,N=64, 8 waves of 64m x 32o, XCD swizzle, XOR chunk
// swizzle, hg-scale flush, atomic epilogue) with a T3+T4+T5 schedule:
//  - TRIPLE-buffered B-tiles (3 x 32 KB); batch(r+2) issued during round r,
//    ONE global_load_lds per phase (4 phases/round).
//  - Counted s_waitcnt vmcnt(4) + raw s_barrier once per round: batch(r+1)'s
//    4 loads stay in flight across the barrier (never vmcnt(0) mid-loop).
//  - Each phase: 4 ds_read_b128 -> setprio(1) -> 8-MFMA cluster -> setprio(0).
//  - hg scales pre-converted to f32 in LDS (no per-round bf16 unpack).
// All waits/barriers are asm with "memory" clobber: the compiler cannot see
// that global_load_lds writes Bl, so the clobber is the fence that keeps
// Bl reads below the barrier.
// ---------------------------------------------------------------------------
__global__ __launch_bounds__(512, 2)
void k_gemm(const unsigned short* __restrict__ Vb,
            const unsigned short* __restrict__ hgbT,
            const unsigned short* __restrict__ xb,
            float* __restrict__ out) {
  __shared__ __align__(16) unsigned short Bl[3][64 * 256];   // 3 x 32 KB
  __shared__ __align__(16) float hgsF[33 * 256];             // 33.8 KB [h_local][m]
  const int tid = threadIdx.x;
  const int lane = tid & 63;
  const int wave = tid >> 6;        // 0..7
  const int l31 = lane & 31;
  const int hi = lane >> 5;
  const int wm = wave & 3;          // m-group (64 rows)
  const int wo = wave >> 2;         // o-half (32 cols)

  // XCD-aware decode: group g = (o-tile, z) pins to XCD g&7; x-blocks stack.
  const int bid = blockIdx.x;       // 0..255
  const int c = bid & 7;
  const int t2 = bid >> 3;
  const int xm = t2 & 15;           // m-block
  const int g8 = t2 >> 4;           // 0..1
  const int grp = c + 8 * g8;       // 0..15
  const int yo = grp & 3;
  const int z = grp >> 2;

  const int m0 = xm * 256;
  const int o0 = yo * 64;
  const int hBeg = (z * HX) >> 2;
  const int hEnd = ((z + 1) * HX) >> 2;
  const int nh = hEnd - hBeg;   // 32,32,32,33

  // ---- stage hg tile as f32 [h_local][m] (h==128 -> 1.0) ----
  for (int idx = tid; idx < nh * 256; idx += 512) {
    const int hl = idx >> 8;
    const int hh = hBeg + hl;
    hgsF[idx] = (hh == HYP) ? 1.0f
                            : bf2f(hgbT[(size_t)hh * BATCH + m0 + (idx & 255)]);
  }

  // ---- preload A fragments (2 m-subtiles x 16 k16-tiles), persistent ----
  const int mrow0 = m0 + wm * 64 + l31;
  const int mrow1 = mrow0 + 32;
  uint4 xf0[16], xf1[16];
#pragma unroll
  for (int j = 0; j < 16; ++j) {
    xf0[j] = *(const uint4*)(xb + (size_t)mrow0 * IN_F + j * 16 + hi * 8);
    xf1[j] = *(const uint4*)(xb + (size_t)mrow1 * IN_F + j * 16 + hi * 8);
  }

  // ---- staging geometry: 2048 chunks of 16B per round, 4 per thread ----
  const int nB = tid >> 5;            // base row (rows nB + 16j)
  const int p5 = tid & 31;            // stored position within row
  const int cs = p5 ^ (nB & 7);       // source chunk (XOR swizzle, self-inverse)
  const unsigned short* gsrc = Vb + (size_t)(o0 + nB) * KP + cs * 8 + (size_t)hBeg * IN_F;

  f32x16 zv;
#pragma unroll
  for (int i = 0; i < 16; ++i) zv[i] = 0.0f;
  f32x16 acc0 = zv, acc1 = zv;
  f32x16 ah0 = zv, ah1 = zv;

  // prologue: batch(0) -> Bl[0], batch(1) -> Bl[1]
#pragma unroll
  for (int j = 0; j < 4; ++j)
    gld_lds16(gsrc + (size_t)j * 16 * KP, &Bl[0][((size_t)tid + 512 * j) * 8]);
#pragma unroll
  for (int j = 0; j < 4; ++j)
    gld_lds16(gsrc + IN_F + (size_t)j * 16 * KP, &Bl[1][((size_t)tid + 512 * j) * 8]);
  // drain hgsF ds_writes (cross-wave visibility via the round-0 entry barrier)
  asm volatile("s_waitcnt lgkmcnt(0)" ::: "memory");

  const int rowb = wo * 32 + l31;
  for (int r = 0; r < nh; ++r) {
    // entry sync: batch(r) resident in Bl[r%3]; batch(r+1)'s 4 loads (the
    // newest) may stay in flight. Last round drains all.
    if (r + 1 < nh) asm volatile("s_waitcnt vmcnt(4)" ::: "memory");
    else            asm volatile("s_waitcnt vmcnt(0)" ::: "memory");
    asm volatile("s_barrier" ::: "memory");

    const unsigned short* bp = &Bl[r % 3][0];
    const bool issue = (r + 2 < nh);
    unsigned short* nxt = &Bl[(r + 2) % 3][0];
    const unsigned short* gs = gsrc + (size_t)(r + 2) * IN_F;

#pragma unroll
    for (int p = 0; p < 4; ++p) {
      if (issue)  // one staging load per phase, 2 rounds ahead
        gld_lds16(gs + (size_t)p * 16 * KP, nxt + ((size_t)tid + 512 * p) * 8);
      short8 bfr[4];
#pragma unroll
      for (int tt = 0; tt < 4; ++tt) {
        const int c0 = p * 8 + tt * 2 + hi;
        const int pr = c0 ^ (l31 & 7);
        bfr[tt] = *(const short8*)(bp + rowb * 256 + pr * 8);
      }
      __builtin_amdgcn_s_setprio(1);
#pragma unroll
      for (int tt = 0; tt < 4; ++tt) {
        const short8 a0 = __builtin_bit_cast(short8, xf0[p * 4 + tt]);
        const short8 a1 = __builtin_bit_cast(short8, xf1[p * 4 + tt]);
        ah0 = __builtin_amdgcn_mfma_f32_32x32x16_bf16(a0, bfr[tt], ah0, 0, 0, 0);
        ah1 = __builtin_amdgcn_mfma_f32_32x32x16_bf16(a1, bfr[tt], ah1, 0, 0, 0);
      }
      __builtin_amdgcn_s_setprio(0);
    }

    // flush: acc += hg * ah (linearity: hg scale applied post-MFMA)
#pragma unroll
    for (int q = 0; q < 4; ++q) {
      const float4 hv0 = *(const float4*)&hgsF[r * 256 + wm * 64 + 4 * hi + q * 8];
      const float4 hv1 = *(const float4*)&hgsF[r * 256 + wm * 64 + 32 + 4 * hi + q * 8];
#pragma unroll
      for (int e = 0; e < 4; ++e) {
        acc0[q * 4 + e] += ((const float*)&hv0)[e] * ah0[q * 4 + e];
        acc1[q * 4 + e] += ((const float*)&hv1)[e] * ah1[q * 4 + e];
      }
    }
    ah0 = zv; ah1 = zv;
    // no trailing barrier: next round's entry barrier orders buffer reuse
    // (writes go to (r+2)%3, which nobody reads in rounds r or r+1).
  }

  // epilogue: atomic accumulate (4 h-splits per output)
  const int mb = m0 + wm * 64 + 4 * hi;
  const int col = o0 + wo * 32 + l31;
#pragma unroll
  for (int g = 0; g < 16; ++g) {
    const int row0 = mb + (g & 3) + 8 * (g >> 2);
    atomicAdd(&out[(size_t)row0 * OUT_F + col], acc0[g]);
    atomicAdd(&out[(size_t)(row0 + 32) * OUT_F + col], acc1[g]);
  }
}

// ---------------------------------------------------------------------------
extern "C" void kernel_launch(void* const* d_in, const int* in_sizes, int n_in,
                              void* d_out, int out_size, void* d_ws, size_t ws_size,
                              hipStream_t stream) {
  const float* x = (const float*)d_in[0];
  const float* W1g = (const float*)d_in[1];
  const float* b1g = (const float*)d_in[2];
  const float* W2g = (const float*)d_in[3];
  const float* b2g = (const float*)d_in[4];
  const float* W1b = (const float*)d_in[5];
  const float* b1b = (const float*)d_in[6];
  const float* W2b = (const float*)d_in[7];
  const float* b2b = (const float*)d_in[8];
  float* out = (float*)d_out;

  char* ws = (char*)d_ws;
  const size_t szV = (size_t)OUT_F * KP * 2;        // 16,908,288
  const size_t szHg = (size_t)HYP * BATCH * 2;      //  1,048,576
  const size_t szXb = (size_t)BATCH * IN_F * 2;     //  2,097,152
  const size_t szW1T = (size_t)256 * 256 * 2;       //    131,072
  unsigned short* Vb = (unsigned short*)ws;
  unsigned short* hgbT = (unsigned short*)(ws + szV);
  unsigned short* xb = (unsigned short*)(ws + szV + szHg);
  unsigned short* W1T = (unsigned short*)(ws + szV + szHg + szXb);
  unsigned short* W2bT = (unsigned short*)(ws + szV + szHg + szXb + szW1T);

  hipLaunchKernelGGL(k_trans, dim3(96), dim3(256), 0, stream, W1g, W1b, W2b, W1T, W2bT);
  hipLaunchKernelGGL(k_prep, dim3(NGEMMP + NVB), dim3(512), 0, stream,
                     x, b1g, b1b, b2b, W2g, b2g, W1T, W2bT, Vb, hgbT, xb, out);
  hipLaunchKernelGGL(k_gemm, dim3(256), dim3(512), 0, stream, Vb, hgbT, xb, out);
}

// Round 6
// 186.082 us; speedup vs baseline: 1.0689x; 1.0689x over previous
//
#include <hip/hip_runtime.h>

#define AS1 __attribute__((address_space(1)))
#define AS3 __attribute__((address_space(3)))

typedef short short8 __attribute__((ext_vector_type(8)));
typedef float f32x16 __attribute__((ext_vector_type(16)));

// Problem constants
#define BATCH 4096
#define IN_F 256
#define OUT_F 256
#define HYP 128
#define HX 129            // HYP + 1 (b2g folded in as extra channel, gain 1.0)
#define KP (HX * IN_F)    // 33024 shorts per V row
#define NGEMMP 32         // prep GEMM blocks (M-tile 128)
#define NVB 516           // V-build blocks (2048 cids each; 256*129*32 / 2048)

__device__ __forceinline__ float bf2f(unsigned short u) {
  unsigned v = ((unsigned)u) << 16;
  float f;
  __builtin_memcpy(&f, &v, 4);
  return f;
}
__device__ __forceinline__ unsigned short f2bf(float f) {
  unsigned u;
  __builtin_memcpy(&u, &f, 4);
  unsigned r = u + 0x7fffu + ((u >> 16) & 1u);  // RTNE
  return (unsigned short)(r >> 16);
}

__device__ __forceinline__ void gld_lds16(const unsigned short* g, unsigned short* s) {
  __builtin_amdgcn_global_load_lds((const AS1 unsigned int*)g, (AS3 unsigned int*)s, 16, 0, 0);
}

// ---------------------------------------------------------------------------
// k_trans: build bf16 transposed weight views so MFMA operands are
// k-contiguous.  W1T[n][k] (n<128: W1g^T, n>=128: W1b^T), W2bT[o][h].
// ---------------------------------------------------------------------------
__global__ __launch_bounds__(256) void k_trans(const float* __restrict__ W1g,
                                               const float* __restrict__ W1b,
                                               const float* __restrict__ W2b,
                                               unsigned short* __restrict__ W1T,
                                               unsigned short* __restrict__ W2bT) {
  const int t = threadIdx.x, b = blockIdx.x;
  if (b < 64) {
#pragma unroll
    for (int i = 0; i < 4; ++i) {
      const int e = b * 1024 + i * 256 + t;   // < 65536
      const int n = e >> 8, k = e & 255;
      const float v = (n < HYP) ? W1g[k * HYP + n] : W1b[k * HYP + (n - HYP)];
      W1T[e] = f2bf(v);
    }
  } else {
#pragma unroll
    for (int i = 0; i < 4; ++i) {
      const int e = (b - 64) * 1024 + i * 256 + t;  // < 32768
      const int o = e >> 7, h = e & 127;
      W2bT[e] = f2bf(W2b[h * OUT_F + o]);
    }
  }
}

// ---------------------------------------------------------------------------
// k_prep: blocks [0,NGEMMP): MFMA prep GEMMs, M-tile 128, 8 waves.
// blocks [NGEMMP, NGEMMP+NVB): V build.  (verified round-2 kernel, unchanged)
// ---------------------------------------------------------------------------
__global__ __launch_bounds__(512) void k_prep(
    const float* __restrict__ x,
    const float* __restrict__ b1g, const float* __restrict__ b1b,
    const float* __restrict__ b2b,
    const float* __restrict__ W2g, const float* __restrict__ b2g,
    const unsigned short* __restrict__ W1T, const unsigned short* __restrict__ W2bT,
    unsigned short* __restrict__ Vb, unsigned short* __restrict__ hgbT,
    unsigned short* __restrict__ xb, float* __restrict__ out) {
  __shared__ __align__(16) unsigned short xS[128 * 256];   // 64 KB, chunk^row&31 swizzle
  __shared__ __align__(16) unsigned short hbS[128 * 128];  // 32 KB, chunk^m&15 swizzle
  const int t = threadIdx.x;

  if (blockIdx.x >= NGEMMP) {
    const int base = (blockIdx.x - NGEMMP) * 2048 + t;
#pragma unroll
    for (int it = 0; it < 4; ++it) {
      const int cid = base + it * 512;
      const int ic = cid & 31;
      const int pair = cid >> 5;        // o*129 + h
      const int h = pair % HX;
      const int o = pair / HX;
      const float* src = (h < HYP) ? (W2g + (size_t)h * (OUT_F * IN_F) + o * IN_F + ic * 8)
                                   : (b2g + o * IN_F + ic * 8);
      const float4 v0 = ((const float4*)src)[0];
      const float4 v1 = ((const float4*)src)[1];
      uint4 pk;
      pk.x = (unsigned)f2bf(v0.x) | ((unsigned)f2bf(v0.y) << 16);
      pk.y = (unsigned)f2bf(v0.z) | ((unsigned)f2bf(v0.w) << 16);
      pk.z = (unsigned)f2bf(v1.x) | ((unsigned)f2bf(v1.y) << 16);
      pk.w = (unsigned)f2bf(v1.z) | ((unsigned)f2bf(v1.w) << 16);
      *(uint4*)(Vb + (size_t)o * KP + h * IN_F + ic * 8) = pk;
    }
    return;
  }

  const int lane = t & 63;
  const int w = t >> 6;            // 0..7
  const int l31 = lane & 31;
  const int hi = lane >> 5;
  const int m0 = blockIdx.x * 128;

#pragma unroll
  for (int j = 0; j < 16; ++j) {
    const int row = j * 8 + w;                       // 0..127, each once
    const float4 v = *(const float4*)(x + (size_t)(m0 + row) * IN_F + lane * 4);
    uint2 pk;
    pk.x = (unsigned)f2bf(v.x) | ((unsigned)f2bf(v.y) << 16);
    pk.y = (unsigned)f2bf(v.z) | ((unsigned)f2bf(v.w) << 16);
    *(uint2*)(xb + (size_t)(m0 + row) * IN_F + lane * 4) = pk;
    const int ch = lane >> 1, half = lane & 1;       // 16B chunk, 8B half
    *(uint2*)(&xS[row * 256 + ((ch ^ (row & 31))) * 8 + half * 4]) = pk;
  }
  __syncthreads();

  const int hA = w * 32 + l31;                       // 0..255 (g: <128, b: >=128)
  uint4 af[16];
#pragma unroll
  for (int kt = 0; kt < 16; ++kt)
    af[kt] = *(const uint4*)(W1T + (size_t)hA * 256 + kt * 16 + hi * 8);

  f32x16 zv;
#pragma unroll
  for (int i = 0; i < 16; ++i) zv[i] = 0.0f;
  f32x16 d0 = zv, d1 = zv, d2 = zv, d3 = zv;
#pragma unroll
  for (int kt = 0; kt < 16; ++kt) {
    const int pos = (kt * 2 + hi) ^ l31;             // (m&31) == l31 for all csub
    const short8 a = __builtin_bit_cast(short8, af[kt]);
#define G1STEP(CS, DD)                                                        \
    {                                                                         \
      const short8 bfrg = *(const short8*)(&xS[(CS * 32 + l31) * 256 + pos * 8]); \
      DD = __builtin_amdgcn_mfma_f32_32x32x16_bf16(a, bfrg, DD, 0, 0, 0);     \
    }
    G1STEP(0, d0) G1STEP(1, d1) G1STEP(2, d2) G1STEP(3, d3)
#undef G1STEP
  }

  if (w < 4) {
    float4 bq[4];
#pragma unroll
    for (int q = 0; q < 4; ++q)
      bq[q] = *(const float4*)(b1g + w * 32 + q * 8 + hi * 4);
#define EPI_G(CS, DD)                                                         \
    {                                                                         \
      const int mcol = m0 + CS * 32 + l31;                                    \
      _Pragma("unroll")                                                       \
      for (int g = 0; g < 16; ++g) {                                          \
        const int h = w * 32 + (g & 3) + 8 * (g >> 2) + 4 * hi;               \
        float v = DD[g] + ((const float*)&bq[g >> 2])[g & 3];                 \
        v = v > 0.f ? v : 0.f;                                                \
        hgbT[(size_t)h * BATCH + mcol] = f2bf(v);                             \
      }                                                                       \
    }
    EPI_G(0, d0) EPI_G(1, d1) EPI_G(2, d2) EPI_G(3, d3)
#undef EPI_G
  } else {
    float4 bq[4];
#pragma unroll
    for (int q = 0; q < 4; ++q)
      bq[q] = *(const float4*)(b1b + (w - 4) * 32 + q * 8 + hi * 4);
#define EPI_B(CS, DD)                                                         \
    {                                                                         \
      const int m = CS * 32 + l31;                                            \
      _Pragma("unroll")                                                       \
      for (int q = 0; q < 4; ++q) {                                           \
        float v0 = DD[q * 4 + 0] + ((const float*)&bq[q])[0];                 \
        float v1 = DD[q * 4 + 1] + ((const float*)&bq[q])[1];                 \
        float v2 = DD[q * 4 + 2] + ((const float*)&bq[q])[2];                 \
        float v3 = DD[q * 4 + 3] + ((const float*)&bq[q])[3];                 \
        v0 = v0 > 0.f ? v0 : 0.f; v1 = v1 > 0.f ? v1 : 0.f;                   \
        v2 = v2 > 0.f ? v2 : 0.f; v3 = v3 > 0.f ? v3 : 0.f;                   \
        uint2 pk;                                                             \
        pk.x = (unsigned)f2bf(v0) | ((unsigned)f2bf(v1) << 16);               \
        pk.y = (unsigned)f2bf(v2) | ((unsigned)f2bf(v3) << 16);               \
        const int chunk = (w - 4) * 4 + q;                                    \
        *(uint2*)(&hbS[m * 128 + ((chunk ^ (m & 15))) * 8 + hi * 4]) = pk;    \
      }                                                                       \
    }
    EPI_B(0, d0) EPI_B(1, d1) EPI_B(2, d2) EPI_B(3, d3)
#undef EPI_B
  }
  __syncthreads();

  const int msub = w & 3, oh = w >> 2;
  const int mA = msub * 32 + l31;
  f32x16 e0 = zv, e1 = zv, e2 = zv, e3 = zv;
#pragma unroll
  for (int kt = 0; kt < 8; ++kt) {
    const int pos = (kt * 2 + hi) ^ (mA & 15);
    const short8 a = *(const short8*)(&hbS[mA * 128 + pos * 8]);
#define G2STEP(OS, EE)                                                        \
    {                                                                         \
      const int orow = oh * 128 + OS * 32 + l31;                              \
      const short8 bb = *(const short8*)(W2bT + (size_t)orow * 128 + kt * 16 + hi * 8); \
      EE = __builtin_amdgcn_mfma_f32_32x32x16_bf16(a, bb, EE, 0, 0, 0);       \
    }
    G2STEP(0, e0) G2STEP(1, e1) G2STEP(2, e2) G2STEP(3, e3)
#undef G2STEP
  }
#define EPI2(OS, EE)                                                          \
  {                                                                           \
    const int o = oh * 128 + OS * 32 + l31;                                   \
    const float bo = b2b[o];                                                  \
    _Pragma("unroll")                                                         \
    for (int g = 0; g < 16; ++g) {                                            \
      const int m = m0 + msub * 32 + (g & 3) + 8 * (g >> 2) + 4 * hi;         \
      out[(size_t)m * OUT_F + o] = EE[g] + bo;                                \
    }                                                                         \
  }
  EPI2(0, e0) EPI2(1, e1) EPI2(2, e2) EPI2(3, e3)
#undef EPI2
}

// ---------------------------------------------------------------------------
// k_gemm: out[b,o] += sum_h hg[b,h] * (sum_i V[o][h*256+i]*x[b,i])
// Round-2 tiling with the FAITHFUL m201-style phase-locked schedule:
//  - 4 phases/round; each phase: {4x ds_read_b128 + 1x global_load_lds}
//    -> s_barrier -> lgkmcnt(0) -> setprio(1) -> 8 MFMA -> setprio(0)
//    -> s_barrier.  (phase-3's closing barrier elided into the next round's
//    entry barrier; flush sits between, read-only.)
//  - TRIPLE-buffered B-tiles; batch(r+2) issued during round r; ONE counted
//    s_waitcnt vmcnt(4) + s_barrier per round (batch r+1's 4 loads stay in
//    flight across it; vmcnt(0) only at the last round).
//  - waitcnt asm carries NO memory clobber (a "memory" clobber makes the
//    compiler's waitcnt pass insert a conservative vmcnt(0) drain first,
//    which killed round 5). Barriers are the compiler-known builtin.
// ---------------------------------------------------------------------------
__global__ __launch_bounds__(512, 2)
void k_gemm(const unsigned short* __restrict__ Vb,
            const unsigned short* __restrict__ hgbT,
            const unsigned short* __restrict__ xb,
            float* __restrict__ out) {
  __shared__ __align__(16) unsigned short Bl[3][64 * 256];   // 3 x 32 KB
  __shared__ __align__(16) float hgsF[33 * 256];             // 33.8 KB [h_local][m]
  const int tid = threadIdx.x;
  const int lane = tid & 63;
  const int wave = tid >> 6;        // 0..7
  const int l31 = lane & 31;
  const int hi = lane >> 5;
  const int wm = wave & 3;          // m-group (64 rows)
  const int wo = wave >> 2;         // o-half (32 cols)

  // XCD-aware decode: group g = (o-tile, z) pins to XCD g&7; x-blocks stack.
  const int bid = blockIdx.x;       // 0..255
  const int c = bid & 7;
  const int t2 = bid >> 3;
  const int xm = t2 & 15;           // m-block
  const int g8 = t2 >> 4;           // 0..1
  const int grp = c + 8 * g8;       // 0..15
  const int yo = grp & 3;
  const int z = grp >> 2;

  const int m0 = xm * 256;
  const int o0 = yo * 64;
  const int hBeg = (z * HX) >> 2;
  const int hEnd = ((z + 1) * HX) >> 2;
  const int nh = hEnd - hBeg;   // 32,32,32,33

  // ---- stage hg tile as f32 [h_local][m] (h==128 -> 1.0) ----
  for (int idx = tid; idx < nh * 256; idx += 512) {
    const int hl = idx >> 8;
    const int hh = hBeg + hl;
    hgsF[idx] = (hh == HYP) ? 1.0f
                            : bf2f(hgbT[(size_t)hh * BATCH + m0 + (idx & 255)]);
  }

  // ---- preload A fragments (2 m-subtiles x 16 k16-tiles), persistent ----
  const int mrow0 = m0 + wm * 64 + l31;
  const int mrow1 = mrow0 + 32;
  uint4 xf0[16], xf1[16];
#pragma unroll
  for (int j = 0; j < 16; ++j) {
    xf0[j] = *(const uint4*)(xb + (size_t)mrow0 * IN_F + j * 16 + hi * 8);
    xf1[j] = *(const uint4*)(xb + (size_t)mrow1 * IN_F + j * 16 + hi * 8);
  }

  // ---- staging geometry: 2048 chunks of 16B per round, 4 per thread ----
  const int nB = tid >> 5;            // base row (rows nB + 16j)
  const int p5 = tid & 31;            // stored position within row
  const int cs = p5 ^ (nB & 7);       // source chunk (XOR swizzle, self-inverse)
  const unsigned short* gsrc = Vb + (size_t)(o0 + nB) * KP + cs * 8 + (size_t)hBeg * IN_F;

  f32x16 zv;
#pragma unroll
  for (int i = 0; i < 16; ++i) zv[i] = 0.0f;
  f32x16 acc0 = zv, acc1 = zv;
  f32x16 ah0 = zv, ah1 = zv;

  // prologue: batch(0) -> Bl[0], batch(1) -> Bl[1]
#pragma unroll
  for (int j = 0; j < 4; ++j)
    gld_lds16(gsrc + (size_t)j * 16 * KP, &Bl[0][((size_t)tid + 512 * j) * 8]);
#pragma unroll
  for (int j = 0; j < 4; ++j)
    gld_lds16(gsrc + IN_F + (size_t)j * 16 * KP, &Bl[1][((size_t)tid + 512 * j) * 8]);
  // drain own hgsF ds_writes before the first entry barrier (cross-wave vis)
  asm volatile("s_waitcnt lgkmcnt(0)");

  const int rowb = wo * 32 + l31;
  for (int r = 0; r < nh; ++r) {
    // ---- round entry: own loads for buf r%3 done; 4 newest (buf r+1) fly ----
    if (r + 1 < nh) asm volatile("s_waitcnt vmcnt(4)");
    else            asm volatile("s_waitcnt vmcnt(0)");
    __builtin_amdgcn_s_barrier();     // buf r%3 now visible to all waves

    const unsigned short* bp = &Bl[r % 3][0];
    const bool issue = (r + 2 < nh);
    unsigned short* nxt = &Bl[(r + 2) % 3][0];
    const unsigned short* gs = gsrc + (size_t)(r + 2) * IN_F;

#pragma unroll
    for (int p = 0; p < 4; ++p) {
      // phase: ds-load register subtile + issue 1 staging load
      short8 bfr[4];
#pragma unroll
      for (int tt = 0; tt < 4; ++tt) {
        const int c0 = p * 8 + tt * 2 + hi;
        const int pr = c0 ^ (l31 & 7);
        bfr[tt] = *(const short8*)(bp + rowb * 256 + pr * 8);
      }
      if (issue)
        gld_lds16(gs + (size_t)p * 16 * KP, nxt + ((size_t)tid + 512 * p) * 8);
      __builtin_amdgcn_s_barrier();
      asm volatile("s_waitcnt lgkmcnt(0)");
      __builtin_amdgcn_s_setprio(1);
#pragma unroll
      for (int tt = 0; tt < 4; ++tt) {
        const short8 a0 = __builtin_bit_cast(short8, xf0[p * 4 + tt]);
        const short8 a1 = __builtin_bit_cast(short8, xf1[p * 4 + tt]);
        ah0 = __builtin_amdgcn_mfma_f32_32x32x16_bf16(a0, bfr[tt], ah0, 0, 0, 0);
        ah1 = __builtin_amdgcn_mfma_f32_32x32x16_bf16(a1, bfr[tt], ah1, 0, 0, 0);
      }
      __builtin_amdgcn_s_setprio(0);
      if (p < 3) __builtin_amdgcn_s_barrier();   // phase-lock (p==3: next
                                                 // round's entry barrier)
    }

    // flush: acc += hg * ah (linearity: hg scale applied post-MFMA)
#pragma unroll
    for (int q = 0; q < 4; ++q) {
      const float4 hv0 = *(const float4*)&hgsF[r * 256 + wm * 64 + 4 * hi + q * 8];
      const float4 hv1 = *(const float4*)&hgsF[r * 256 + wm * 64 + 32 + 4 * hi + q * 8];
#pragma unroll
      for (int e = 0; e < 4; ++e) {
        acc0[q * 4 + e] += ((const float*)&hv0)[e] * ah0[q * 4 + e];
        acc1[q * 4 + e] += ((const float*)&hv1)[e] * ah1[q * 4 + e];
      }
    }
    ah0 = zv; ah1 = zv;
  }

  // epilogue: atomic accumulate (4 h-splits per output)
  const int mb = m0 + wm * 64 + 4 * hi;
  const int col = o0 + wo * 32 + l31;
#pragma unroll
  for (int g = 0; g < 16; ++g) {
    const int row0 = mb + (g & 3) + 8 * (g >> 2);
    atomicAdd(&out[(size_t)row0 * OUT_F + col], acc0[g]);
    atomicAdd(&out[(size_t)(row0 + 32) * OUT_F + col], acc1[g]);
  }
}

// ---------------------------------------------------------------------------
extern "C" void kernel_launch(void* const* d_in, const int* in_sizes, int n_in,
                              void* d_out, int out_size, void* d_ws, size_t ws_size,
                              hipStream_t stream) {
  const float* x = (const float*)d_in[0];
  const float* W1g = (const float*)d_in[1];
  const float* b1g = (const float*)d_in[2];
  const float* W2g = (const float*)d_in[3];
  const float* b2g = (const float*)d_in[4];
  const float* W1b = (const float*)d_in[5];
  const float* b1b = (const float*)d_in[6];
  const float* W2b = (const float*)d_in[7];
  const float* b2b = (const float*)d_in[8];
  float* out = (float*)d_out;

  char* ws = (char*)d_ws;
  const size_t szV = (size_t)OUT_F * KP * 2;        // 16,908,288
  const size_t szHg = (size_t)HYP * BATCH * 2;      //  1,048,576
  const size_t szXb = (size_t)BATCH * IN_F * 2;     //  2,097,152
  const size_t szW1T = (size_t)256 * 256 * 2;       //    131,072
  unsigned short* Vb = (unsigned short*)ws;
  unsigned short* hgbT = (unsigned short*)(ws + szV);
  unsigned short* xb = (unsigned short*)(ws + szV + szHg);
  unsigned short* W1T = (unsigned short*)(ws + szV + szHg + szXb);
  unsigned short* W2bT = (unsigned short*)(ws + szV + szHg + szXb + szW1T);

  hipLaunchKernelGGL(k_trans, dim3(96), dim3(256), 0, stream, W1g, W1b, W2b, W1T, W2bT);
  hipLaunchKernelGGL(k_prep, dim3(NGEMMP + NVB), dim3(512), 0, stream,
                     x, b1g, b1b, b2b, W2g, b2g, W1T, W2bT, Vb, hgbT, xb, out);
  hipLaunchKernelGGL(k_gemm, dim3(256), dim3(512), 0, stream, Vb, hgbT, xb, out);
}

// Round 7
// 184.623 us; speedup vs baseline: 1.0774x; 1.0079x over previous
//
#include <hip/hip_runtime.h>

#define AS1 __attribute__((address_space(1)))
#define AS3 __attribute__((address_space(3)))

typedef short short8 __attribute__((ext_vector_type(8)));
typedef float f32x16 __attribute__((ext_vector_type(16)));
typedef unsigned short ushort4v __attribute__((ext_vector_type(4)));

// Problem constants
#define BATCH 4096
#define IN_F 256
#define OUT_F 256
#define HYP 128
#define HX 129            // HYP + 1 (b2g folded in as extra channel, gain 1.0)
#define KP (HX * IN_F)    // 33024 shorts per V row
#define NGEMMP 32         // prep GEMM blocks (M-tile 128)
#define NVB 516           // V-build blocks (2048 cids each; 256*129*32 / 2048)

__device__ __forceinline__ float bf2f(unsigned short u) {
  unsigned v = ((unsigned)u) << 16;
  float f;
  __builtin_memcpy(&f, &v, 4);
  return f;
}
__device__ __forceinline__ unsigned short f2bf(float f) {
  unsigned u;
  __builtin_memcpy(&u, &f, 4);
  unsigned r = u + 0x7fffu + ((u >> 16) & 1u);  // RTNE
  return (unsigned short)(r >> 16);
}

__device__ __forceinline__ void gld_lds16(const unsigned short* g, unsigned short* s) {
  __builtin_amdgcn_global_load_lds((const AS1 unsigned int*)g, (AS3 unsigned int*)s, 16, 0, 0);
}

// ---------------------------------------------------------------------------
// k_trans: build bf16 transposed weight views so MFMA operands are
// k-contiguous.  W1T[n][k] (n<128: W1g^T, n>=128: W1b^T), W2bT[o][h].
// ---------------------------------------------------------------------------
__global__ __launch_bounds__(256) void k_trans(const float* __restrict__ W1g,
                                               const float* __restrict__ W1b,
                                               const float* __restrict__ W2b,
                                               unsigned short* __restrict__ W1T,
                                               unsigned short* __restrict__ W2bT) {
  const int t = threadIdx.x, b = blockIdx.x;
  if (b < 64) {
#pragma unroll
    for (int i = 0; i < 4; ++i) {
      const int e = b * 1024 + i * 256 + t;   // < 65536
      const int n = e >> 8, k = e & 255;
      const float v = (n < HYP) ? W1g[k * HYP + n] : W1b[k * HYP + (n - HYP)];
      W1T[e] = f2bf(v);
    }
  } else {
#pragma unroll
    for (int i = 0; i < 4; ++i) {
      const int e = (b - 64) * 1024 + i * 256 + t;  // < 32768
      const int o = e >> 7, h = e & 127;
      W2bT[e] = f2bf(W2b[h * OUT_F + o]);
    }
  }
}

// ---------------------------------------------------------------------------
// k_prep: blocks [0,NGEMMP): MFMA prep GEMMs, M-tile 128, 8 waves.
// blocks [NGEMMP, NGEMMP+NVB): V build.  (verified round-2 kernel, unchanged)
// ---------------------------------------------------------------------------
__global__ __launch_bounds__(512) void k_prep(
    const float* __restrict__ x,
    const float* __restrict__ b1g, const float* __restrict__ b1b,
    const float* __restrict__ b2b,
    const float* __restrict__ W2g, const float* __restrict__ b2g,
    const unsigned short* __restrict__ W1T, const unsigned short* __restrict__ W2bT,
    unsigned short* __restrict__ Vb, unsigned short* __restrict__ hgbT,
    unsigned short* __restrict__ xb, float* __restrict__ out) {
  __shared__ __align__(16) unsigned short xS[128 * 256];   // 64 KB, chunk^row&31 swizzle
  __shared__ __align__(16) unsigned short hbS[128 * 128];  // 32 KB, chunk^m&15 swizzle
  const int t = threadIdx.x;

  if (blockIdx.x >= NGEMMP) {
    const int base = (blockIdx.x - NGEMMP) * 2048 + t;
#pragma unroll
    for (int it = 0; it < 4; ++it) {
      const int cid = base + it * 512;
      const int ic = cid & 31;
      const int pair = cid >> 5;        // o*129 + h
      const int h = pair % HX;
      const int o = pair / HX;
      const float* src = (h < HYP) ? (W2g + (size_t)h * (OUT_F * IN_F) + o * IN_F + ic * 8)
                                   : (b2g + o * IN_F + ic * 8);
      const float4 v0 = ((const float4*)src)[0];
      const float4 v1 = ((const float4*)src)[1];
      uint4 pk;
      pk.x = (unsigned)f2bf(v0.x) | ((unsigned)f2bf(v0.y) << 16);
      pk.y = (unsigned)f2bf(v0.z) | ((unsigned)f2bf(v0.w) << 16);
      pk.z = (unsigned)f2bf(v1.x) | ((unsigned)f2bf(v1.y) << 16);
      pk.w = (unsigned)f2bf(v1.z) | ((unsigned)f2bf(v1.w) << 16);
      *(uint4*)(Vb + (size_t)o * KP + h * IN_F + ic * 8) = pk;
    }
    return;
  }

  const int lane = t & 63;
  const int w = t >> 6;            // 0..7
  const int l31 = lane & 31;
  const int hi = lane >> 5;
  const int m0 = blockIdx.x * 128;

#pragma unroll
  for (int j = 0; j < 16; ++j) {
    const int row = j * 8 + w;                       // 0..127, each once
    const float4 v = *(const float4*)(x + (size_t)(m0 + row) * IN_F + lane * 4);
    uint2 pk;
    pk.x = (unsigned)f2bf(v.x) | ((unsigned)f2bf(v.y) << 16);
    pk.y = (unsigned)f2bf(v.z) | ((unsigned)f2bf(v.w) << 16);
    *(uint2*)(xb + (size_t)(m0 + row) * IN_F + lane * 4) = pk;
    const int ch = lane >> 1, half = lane & 1;       // 16B chunk, 8B half
    *(uint2*)(&xS[row * 256 + ((ch ^ (row & 31))) * 8 + half * 4]) = pk;
  }
  __syncthreads();

  const int hA = w * 32 + l31;                       // 0..255 (g: <128, b: >=128)
  uint4 af[16];
#pragma unroll
  for (int kt = 0; kt < 16; ++kt)
    af[kt] = *(const uint4*)(W1T + (size_t)hA * 256 + kt * 16 + hi * 8);

  f32x16 zv;
#pragma unroll
  for (int i = 0; i < 16; ++i) zv[i] = 0.0f;
  f32x16 d0 = zv, d1 = zv, d2 = zv, d3 = zv;
#pragma unroll
  for (int kt = 0; kt < 16; ++kt) {
    const int pos = (kt * 2 + hi) ^ l31;             // (m&31) == l31 for all csub
    const short8 a = __builtin_bit_cast(short8, af[kt]);
#define G1STEP(CS, DD)                                                        \
    {                                                                         \
      const short8 bfrg = *(const short8*)(&xS[(CS * 32 + l31) * 256 + pos * 8]); \
      DD = __builtin_amdgcn_mfma_f32_32x32x16_bf16(a, bfrg, DD, 0, 0, 0);     \
    }
    G1STEP(0, d0) G1STEP(1, d1) G1STEP(2, d2) G1STEP(3, d3)
#undef G1STEP
  }

  if (w < 4) {
    float4 bq[4];
#pragma unroll
    for (int q = 0; q < 4; ++q)
      bq[q] = *(const float4*)(b1g + w * 32 + q * 8 + hi * 4);
#define EPI_G(CS, DD)                                                         \
    {                                                                         \
      const int mcol = m0 + CS * 32 + l31;                                    \
      _Pragma("unroll")                                                       \
      for (int g = 0; g < 16; ++g) {                                          \
        const int h = w * 32 + (g & 3) + 8 * (g >> 2) + 4 * hi;               \
        float v = DD[g] + ((const float*)&bq[g >> 2])[g & 3];                 \
        v = v > 0.f ? v : 0.f;                                                \
        hgbT[(size_t)h * BATCH + mcol] = f2bf(v);                             \
      }                                                                       \
    }
    EPI_G(0, d0) EPI_G(1, d1) EPI_G(2, d2) EPI_G(3, d3)
#undef EPI_G
  } else {
    float4 bq[4];
#pragma unroll
    for (int q = 0; q < 4; ++q)
      bq[q] = *(const float4*)(b1b + (w - 4) * 32 + q * 8 + hi * 4);
#define EPI_B(CS, DD)                                                         \
    {                                                                         \
      const int m = CS * 32 + l31;                                            \
      _Pragma("unroll")                                                       \
      for (int q = 0; q < 4; ++q) {                                           \
        float v0 = DD[q * 4 + 0] + ((const float*)&bq[q])[0];                 \
        float v1 = DD[q * 4 + 1] + ((const float*)&bq[q])[1];                 \
        float v2 = DD[q * 4 + 2] + ((const float*)&bq[q])[2];                 \
        float v3 = DD[q * 4 + 3] + ((const float*)&bq[q])[3];                 \
        v0 = v0 > 0.f ? v0 : 0.f; v1 = v1 > 0.f ? v1 : 0.f;                   \
        v2 = v2 > 0.f ? v2 : 0.f; v3 = v3 > 0.f ? v3 : 0.f;                   \
        uint2 pk;                                                             \
        pk.x = (unsigned)f2bf(v0) | ((unsigned)f2bf(v1) << 16);               \
        pk.y = (unsigned)f2bf(v2) | ((unsigned)f2bf(v3) << 16);               \
        const int chunk = (w - 4) * 4 + q;                                    \
        *(uint2*)(&hbS[m * 128 + ((chunk ^ (m & 15))) * 8 + hi * 4]) = pk;    \
      }                                                                       \
    }
    EPI_B(0, d0) EPI_B(1, d1) EPI_B(2, d2) EPI_B(3, d3)
#undef EPI_B
  }
  __syncthreads();

  const int msub = w & 3, oh = w >> 2;
  const int mA = msub * 32 + l31;
  f32x16 e0 = zv, e1 = zv, e2 = zv, e3 = zv;
#pragma unroll
  for (int kt = 0; kt < 8; ++kt) {
    const int pos = (kt * 2 + hi) ^ (mA & 15);
    const short8 a = *(const short8*)(&hbS[mA * 128 + pos * 8]);
#define G2STEP(OS, EE)                                                        \
    {                                                                         \
      const int orow = oh * 128 + OS * 32 + l31;                              \
      const short8 bb = *(const short8*)(W2bT + (size_t)orow * 128 + kt * 16 + hi * 8); \
      EE = __builtin_amdgcn_mfma_f32_32x32x16_bf16(a, bb, EE, 0, 0, 0);       \
    }
    G2STEP(0, e0) G2STEP(1, e1) G2STEP(2, e2) G2STEP(3, e3)
#undef G2STEP
  }
#define EPI2(OS, EE)                                                          \
  {                                                                           \
    const int o = oh * 128 + OS * 32 + l31;                                   \
    const float bo = b2b[o];                                                  \
    _Pragma("unroll")                                                         \
    for (int g = 0; g < 16; ++g) {                                            \
      const int m = m0 + msub * 32 + (g & 3) + 8 * (g >> 2) + 4 * hi;         \
      out[(size_t)m * OUT_F + o] = EE[g] + bo;                                \
    }                                                                         \
  }
  EPI2(0, e0) EPI2(1, e1) EPI2(2, e2) EPI2(3, e3)
#undef EPI2
}

// ---------------------------------------------------------------------------
// k_gemm: out[b,o] += sum_h hg[b,h] * (sum_i V[o][h*256+i]*x[b,i])
// Round-2 verified inner structure (double-buffer + issue-ahead +
// __syncthreads), HALVED block: 256 threads = 4 waves, M-tile 128, N=64,
// per-wave 64m x 32o unchanged. LDS = 2x32KB dbuf + bf16 hg tile = 74 KB
// -> 2 independent blocks/CU. Per-CU totals (LDS reads, MFMA, staging) are
// identical to the 512-thread version, but the two co-resident blocks share
// no barrier: one block's LDS burst overlaps the other's MFMA burst (m114
// wave-independence), breaking the lockstep serialization that pinned all
// schedule variants at 88.5 us. ah reset removed via C=zv on each round's
// first MFMA.
// ---------------------------------------------------------------------------
__global__ __launch_bounds__(256, 2)
void k_gemm(const unsigned short* __restrict__ Vb,
            const unsigned short* __restrict__ hgbT,
            const unsigned short* __restrict__ xb,
            float* __restrict__ out) {
  __shared__ __align__(16) unsigned short Bl[2][64 * 256];   // 2 x 32 KB
  __shared__ __align__(16) unsigned short hgs[33 * 128];     // 8.25 KB [h_local][m] bf16
  const int tid = threadIdx.x;
  const int lane = tid & 63;
  const int wave = tid >> 6;        // 0..3
  const int l31 = lane & 31;
  const int hi = lane >> 5;
  const int wm = wave & 1;          // m-group (64 rows)
  const int wo = wave >> 1;         // o-half (32 cols)

  // XCD-aware decode: 512 blocks; group g = (o-tile, z) pins to XCD g&7.
  const int bid = blockIdx.x;       // 0..511
  const int c = bid & 7;
  const int t2 = bid >> 3;          // 0..63
  const int xm = t2 & 31;           // m-block (32 of them)
  const int g8 = t2 >> 5;           // 0..1
  const int grp = c + 8 * g8;       // 0..15
  const int yo = grp & 3;
  const int z = grp >> 2;

  const int m0 = xm * 128;
  const int o0 = yo * 64;
  const int hBeg = (z * HX) >> 2;
  const int hEnd = ((z + 1) * HX) >> 2;
  const int nh = hEnd - hBeg;   // 32,32,32,33

  // ---- stage hg tile [h_local][m] bf16 (h==128 -> 1.0) ----
  for (int idx = tid; idx < nh * 128; idx += 256) {
    const int hl = idx >> 7;
    const int hh = hBeg + hl;
    hgs[idx] = (hh == HYP) ? (unsigned short)0x3F80
                           : hgbT[(size_t)hh * BATCH + m0 + (idx & 127)];
  }

  // ---- preload A fragments (2 m-subtiles x 16 k16-tiles), persistent ----
  const int mrow0 = m0 + wm * 64 + l31;
  const int mrow1 = mrow0 + 32;
  uint4 xf0[16], xf1[16];
#pragma unroll
  for (int j = 0; j < 16; ++j) {
    xf0[j] = *(const uint4*)(xb + (size_t)mrow0 * IN_F + j * 16 + hi * 8);
    xf1[j] = *(const uint4*)(xb + (size_t)mrow1 * IN_F + j * 16 + hi * 8);
  }

  // ---- staging geometry: 2048 chunks of 16B per round, 8 per thread ----
  const int nB = tid >> 5;            // base row (rows nB + 8j)
  const int p5 = tid & 31;            // stored position within row
  const int cs = p5 ^ (nB & 7);       // source chunk (XOR swizzle, self-inverse)
  const unsigned short* gsrc = Vb + (size_t)(o0 + nB) * KP + cs * 8 + (size_t)hBeg * IN_F;

  f32x16 zv;
#pragma unroll
  for (int i = 0; i < 16; ++i) zv[i] = 0.0f;
  f32x16 acc0 = zv, acc1 = zv;
  f32x16 ah0 = zv, ah1 = zv;

  // prologue: stage round 0 into buf 0 (rows nB + 8j)
#pragma unroll
  for (int j = 0; j < 8; ++j)
    gld_lds16(gsrc + (size_t)j * 8 * KP, &Bl[0][((size_t)tid + 256 * j) * 8]);
  __syncthreads();

  const int rowb = wo * 32 + l31;
  for (int r = 0; r < nh; ++r) {
    const int buf = r & 1;
    if (r + 1 < nh) {  // issue next round's staging ahead of compute
      const unsigned short* gs = gsrc + (size_t)(r + 1) * IN_F;
#pragma unroll
      for (int j = 0; j < 8; ++j)
        gld_lds16(gs + (size_t)j * 8 * KP, &Bl[buf ^ 1][((size_t)tid + 256 * j) * 8]);
    }
    const unsigned short* bp = &Bl[buf][0];
#pragma unroll
    for (int ic = 0; ic < 4; ++ic) {
#pragma unroll
      for (int t = 0; t < 4; ++t) {
        const int c0 = ic * 8 + t * 2 + hi;
        const int pr = c0 ^ (l31 & 7);
        const short8 b0 = *(const short8*)(bp + rowb * 256 + pr * 8);
        const short8 a0 = __builtin_bit_cast(short8, xf0[ic * 4 + t]);
        const short8 a1 = __builtin_bit_cast(short8, xf1[ic * 4 + t]);
        if (ic == 0 && t == 0) {  // C = 0: kills the per-round ah reset
          ah0 = __builtin_amdgcn_mfma_f32_32x32x16_bf16(a0, b0, zv, 0, 0, 0);
          ah1 = __builtin_amdgcn_mfma_f32_32x32x16_bf16(a1, b0, zv, 0, 0, 0);
        } else {
          ah0 = __builtin_amdgcn_mfma_f32_32x32x16_bf16(a0, b0, ah0, 0, 0, 0);
          ah1 = __builtin_amdgcn_mfma_f32_32x32x16_bf16(a1, b0, ah1, 0, 0, 0);
        }
      }
    }
    // flush: acc += hg * ah (linearity: hg scale applied post-MFMA)
#pragma unroll
    for (int q = 0; q < 4; ++q) {
      const ushort4v v0 = *(const ushort4v*)&hgs[r * 128 + wm * 64 + 4 * hi + q * 8];
      const ushort4v v1 = *(const ushort4v*)&hgs[r * 128 + wm * 64 + 32 + 4 * hi + q * 8];
#pragma unroll
      for (int e = 0; e < 4; ++e) {
        acc0[q * 4 + e] += bf2f(v0[e]) * ah0[q * 4 + e];
        acc1[q * 4 + e] += bf2f(v1[e]) * ah1[q * 4 + e];
      }
    }
    __syncthreads();  // drains next-buf loads (issued a round ago) + buf reuse
  }

  // epilogue: atomic accumulate (4 h-splits per output)
  const int mb = m0 + wm * 64 + 4 * hi;
  const int col = o0 + wo * 32 + l31;
#pragma unroll
  for (int g = 0; g < 16; ++g) {
    const int row0 = mb + (g & 3) + 8 * (g >> 2);
    atomicAdd(&out[(size_t)row0 * OUT_F + col], acc0[g]);
    atomicAdd(&out[(size_t)(row0 + 32) * OUT_F + col], acc1[g]);
  }
}

// ---------------------------------------------------------------------------
extern "C" void kernel_launch(void* const* d_in, const int* in_sizes, int n_in,
                              void* d_out, int out_size, void* d_ws, size_t ws_size,
                              hipStream_t stream) {
  const float* x = (const float*)d_in[0];
  const float* W1g = (const float*)d_in[1];
  const float* b1g = (const float*)d_in[2];
  const float* W2g = (const float*)d_in[3];
  const float* b2g = (const float*)d_in[4];
  const float* W1b = (const float*)d_in[5];
  const float* b1b = (const float*)d_in[6];
  const float* W2b = (const float*)d_in[7];
  const float* b2b = (const float*)d_in[8];
  float* out = (float*)d_out;

  char* ws = (char*)d_ws;
  const size_t szV = (size_t)OUT_F * KP * 2;        // 16,908,288
  const size_t szHg = (size_t)HYP * BATCH * 2;      //  1,048,576
  const size_t szXb = (size_t)BATCH * IN_F * 2;     //  2,097,152
  const size_t szW1T = (size_t)256 * 256 * 2;       //    131,072
  unsigned short* Vb = (unsigned short*)ws;
  unsigned short* hgbT = (unsigned short*)(ws + szV);
  unsigned short* xb = (unsigned short*)(ws + szV + szHg);
  unsigned short* W1T = (unsigned short*)(ws + szV + szHg + szXb);
  unsigned short* W2bT = (unsigned short*)(ws + szV + szHg + szXb + szW1T);

  hipLaunchKernelGGL(k_trans, dim3(96), dim3(256), 0, stream, W1g, W1b, W2b, W1T, W2bT);
  hipLaunchKernelGGL(k_prep, dim3(NGEMMP + NVB), dim3(512), 0, stream,
                     x, b1g, b1b, b2b, W2g, b2g, W1T, W2bT, Vb, hgbT, xb, out);
  hipLaunchKernelGGL(k_gemm, dim3(512), dim3(256), 0, stream, Vb, hgbT, xb, out);
}